// Round 8
// baseline (1006.374 us; speedup 1.0000x reference)
//
#include <hip/hip_runtime.h>

#define D_MODEL 512
#define SEQ     4096
#define BATCH   4
#define M_TOT   (BATCH*SEQ)   // 16384
#define WS_NEEDED ((size_t)2 * M_TOT * D_MODEL * 2)   // node_bf + nodeT_bf: 32 MiB

typedef float  f32x4  __attribute__((ext_vector_type(4)));
typedef __bf16 bf16x8 __attribute__((ext_vector_type(8)));

union FU { float f; unsigned int u; };
__device__ __forceinline__ unsigned short f_to_bf16(float f) {
    FU c; c.f = f;
    unsigned int r = c.u + 0x7fffu + ((c.u >> 16) & 1u);   // RNE
    return (unsigned short)(r >> 16);
}
__device__ __forceinline__ unsigned int pack_bf16(float a, float b) {
    return (unsigned int)f_to_bf16(a) | ((unsigned int)f_to_bf16(b) << 16);
}

// -------- K1: node_bf = relu(x @ W^T + b) via MFMA; + transposed copy ------
extern "C" __global__ __launch_bounds__(256) void proj_kernel(
        const float* __restrict__ x, const float* __restrict__ w,
        const float* __restrict__ bias,
        unsigned short* __restrict__ node_bf, unsigned short* __restrict__ nodeT_bf) {
    __shared__ short Xs[64][72];   // bf16 bits, +8 pad (also transpose buf in epilogue)
    __shared__ short Ws[64][72];
    const int tid  = threadIdx.x;
    const int row0 = blockIdx.x * 64;
    const int col0 = blockIdx.y * 64;
    const int lane = tid & 63;
    const int wv   = tid >> 6;
    const int lr   = lane & 15;
    const int quad = lane >> 4;

    f32x4 acc[4];
    #pragma unroll
    for (int s = 0; s < 4; ++s) acc[s] = (f32x4){0.f,0.f,0.f,0.f};

    for (int kc = 0; kc < D_MODEL; kc += 64) {
        // stage 64 rows x 64 k of x and W, fp32 -> bf16 (1024 float4 slots, 4/thread)
        #pragma unroll
        for (int p = 0; p < 2; ++p) {
            int slot = p*256 + tid;            // 0..511
            int r  = slot >> 3, c4 = (slot & 7) * 8;   // 8 float4 per row-half... 64 k = 16 float4
            // use 2 float4 per slot-row mapping: r over 64 rows, c4 over 64 k in steps of 8
            float4 a0 = *(const float4*)(x + (size_t)(row0 + r)*D_MODEL + kc + c4);
            float4 a1 = *(const float4*)(x + (size_t)(row0 + r)*D_MODEL + kc + c4 + 4);
            *(unsigned int*)&Xs[r][c4+0] = pack_bf16(a0.x, a0.y);
            *(unsigned int*)&Xs[r][c4+2] = pack_bf16(a0.z, a0.w);
            *(unsigned int*)&Xs[r][c4+4] = pack_bf16(a1.x, a1.y);
            *(unsigned int*)&Xs[r][c4+6] = pack_bf16(a1.z, a1.w);
            float4 b0 = *(const float4*)(w + (size_t)(col0 + r)*D_MODEL + kc + c4);
            float4 b1 = *(const float4*)(w + (size_t)(col0 + r)*D_MODEL + kc + c4 + 4);
            *(unsigned int*)&Ws[r][c4+0] = pack_bf16(b0.x, b0.y);
            *(unsigned int*)&Ws[r][c4+2] = pack_bf16(b0.z, b0.w);
            *(unsigned int*)&Ws[r][c4+4] = pack_bf16(b1.x, b1.y);
            *(unsigned int*)&Ws[r][c4+6] = pack_bf16(b1.z, b1.w);
        }
        __syncthreads();
        #pragma unroll
        for (int t = 0; t < 2; ++t) {
            bf16x8 a = *reinterpret_cast<const bf16x8*>(&Xs[wv*16 + lr][t*32 + quad*8]);
            #pragma unroll
            for (int s = 0; s < 4; ++s) {
                bf16x8 bb = *reinterpret_cast<const bf16x8*>(&Ws[s*16 + lr][t*32 + quad*8]);
                acc[s] = __builtin_amdgcn_mfma_f32_16x16x32_bf16(a, bb, acc[s], 0, 0, 0);
            }
        }
        __syncthreads();
    }
    // epilogue: bias + relu -> bf16; node direct; transpose tile into Xs for nodeT
    #pragma unroll
    for (int s = 0; s < 4; ++s) {
        int n = col0 + s*16 + lr;
        float bv = bias[n];
        #pragma unroll
        for (int r = 0; r < 4; ++r) {
            int m_local = wv*16 + quad*4 + r;   // C/D: row=quad*4+reg, col=lr (m89, R7-verified)
            float v = acc[s][r] + bv;
            v = v > 0.0f ? v : 0.0f;
            unsigned short us = f_to_bf16(v);
            node_bf[(size_t)(row0 + m_local)*D_MODEL + n] = us;
            Xs[s*16 + lr][m_local] = (short)us;   // T[n_local][m_local]
        }
    }
    __syncthreads();
    {
        const int b = row0 >> 12, si0 = row0 & 4095;   // tile never crosses batch boundary
        #pragma unroll
        for (int p = 0; p < 2; ++p) {
            int slot = p*256 + tid;
            int r = slot >> 3, c8 = (slot & 7) * 8;    // 64 rows x 8 int4
            int4 val = *(int4*)&Xs[r][c8];
            *(int4*)&nodeT_bf[((size_t)(b*D_MODEL + col0 + r))*SEQ + si0 + c8] = val;
        }
    }
}

// -------- K2: flash attention via MFMA, d-chunked LDS (24 KB) --------------
// LDS: Ks 32*136*2=8704 + Vt 128*40*2=10240 + Ps 4*16*40*2=5120 = 24064 B
extern "C" __global__ __launch_bounds__(256, 2) void flash_kernel(
        const unsigned short* __restrict__ node,
        const unsigned short* __restrict__ nodeT,
        float* __restrict__ out) {
    __shared__ short Ks[32][136];     // 32 keys x 128-d chunk, +8 pad
    __shared__ short Vt[128][40];     // 128-d chunk x 32 keys, +8 pad
    __shared__ short Ps[4][16][40];   // per-wave P tile, +8 pad
    const int tid  = threadIdx.x;
    const int lane = tid & 63;
    const int wv   = tid >> 6;
    const int lr   = lane & 15;
    const int quad = lane >> 4;
    const int bb   = blockIdx.y;
    const int q0   = blockIdx.x * 64;

    const unsigned short* nb  = node  + (size_t)bb * SEQ * D_MODEL;
    const unsigned short* ntb = nodeT + (size_t)bb * D_MODEL * SEQ;

    // Q fragments: A[m=lr][k = i*32 + quad*8 + j]
    bf16x8 qf[16];
    const int qrow = q0 + wv*16 + lr;
    #pragma unroll
    for (int t = 0; t < 16; ++t)
        qf[t] = *reinterpret_cast<const bf16x8*>(&nb[(size_t)qrow*D_MODEL + t*32 + quad*8]);

    f32x4 o[32];
    #pragma unroll
    for (int n = 0; n < 32; ++n) o[n] = (f32x4){0.f,0.f,0.f,0.f};
    float m_run[4] = {-3.0e38f,-3.0e38f,-3.0e38f,-3.0e38f};
    float l_run[4] = {0.f,0.f,0.f,0.f};

    for (int kt = 0; kt < SEQ/32; ++kt) {
        // ---- S = Q K^T accumulated over 4 d-chunks of 128 ----
        f32x4 sacc[2];
        sacc[0] = (f32x4){0.f,0.f,0.f,0.f};
        sacc[1] = (f32x4){0.f,0.f,0.f,0.f};
        #pragma unroll
        for (int dc = 0; dc < 4; ++dc) {
            // stage 32 keys x 128 d (512 int4, 2/thread)
            #pragma unroll
            for (int p = 0; p < 2; ++p) {
                int slot = p*256 + tid;
                int r = slot >> 4, c8 = (slot & 15) * 8;
                *(int4*)&Ks[r][c8] =
                    *(const int4*)&nb[(size_t)(kt*32 + r)*D_MODEL + dc*128 + c8];
            }
            __syncthreads();
            #pragma unroll
            for (int t = 0; t < 4; ++t) {
                #pragma unroll
                for (int s = 0; s < 2; ++s) {
                    bf16x8 kb = *reinterpret_cast<const bf16x8*>(&Ks[s*16 + lr][t*32 + quad*8]);
                    sacc[s] = __builtin_amdgcn_mfma_f32_16x16x32_bf16(qf[dc*4 + t], kb, sacc[s], 0, 0, 0);
                }
            }
            __syncthreads();
        }

        // ---- online softmax (C/D: row=quad*4+r, col=lr) ----
        float alpha[4];
        #pragma unroll
        for (int r = 0; r < 4; ++r) {
            float mx = fmaxf(sacc[0][r], sacc[1][r]);
            #pragma unroll
            for (int off = 1; off < 16; off <<= 1)
                mx = fmaxf(mx, __shfl_xor(mx, off));
            float mnew = fmaxf(m_run[r], mx);
            alpha[r] = __expf(m_run[r] - mnew);
            float p0 = __expf(sacc[0][r] - mnew);
            float p1 = __expf(sacc[1][r] - mnew);
            m_run[r] = mnew;
            float rs = p0 + p1;
            #pragma unroll
            for (int off = 1; off < 16; off <<= 1)
                rs += __shfl_xor(rs, off);
            l_run[r] = l_run[r]*alpha[r] + rs;
            Ps[wv][quad*4 + r][lr]      = (short)f_to_bf16(p0);
            Ps[wv][quad*4 + r][16 + lr] = (short)f_to_bf16(p1);
        }
        #pragma unroll
        for (int n = 0; n < 32; ++n) {
            #pragma unroll
            for (int r = 0; r < 4; ++r) o[n][r] *= alpha[r];
        }
        // P fragment: A[m=lr][k=quad*8+j] (same-wave LDS round-trip)
        bf16x8 pa = *reinterpret_cast<const bf16x8*>(&Ps[wv][lr][quad*8]);

        // ---- O += P V over 4 d-chunks of 128 ----
        #pragma unroll
        for (int dc = 0; dc < 4; ++dc) {
            #pragma unroll
            for (int p = 0; p < 2; ++p) {
                int slot = p*256 + tid;
                int dd = slot >> 2, c8 = (slot & 3) * 8;
                *(int4*)&Vt[dd][c8] =
                    *(const int4*)&ntb[(size_t)(dc*128 + dd)*SEQ + kt*32 + c8];
            }
            __syncthreads();
            #pragma unroll
            for (int n = 0; n < 8; ++n) {
                bf16x8 vb = *reinterpret_cast<const bf16x8*>(&Vt[n*16 + lr][quad*8]);
                o[dc*8 + n] = __builtin_amdgcn_mfma_f32_16x16x32_bf16(pa, vb, o[dc*8 + n], 0, 0, 0);
            }
            __syncthreads();
        }
    }

    // epilogue: out = O / l (fp32); o[n] covers d = n*16 + lr
    #pragma unroll
    for (int r = 0; r < 4; ++r) {
        float inv = 1.0f / l_run[r];
        int row = q0 + wv*16 + quad*4 + r;
        float* obase = out + ((size_t)bb * SEQ + row) * D_MODEL;
        #pragma unroll
        for (int n = 0; n < 32; ++n)
            obase[n*16 + lr] = o[n][r] * inv;
    }
}

extern "C" void kernel_launch(void* const* d_in, const int* in_sizes, int n_in,
                              void* d_out, int out_size, void* d_ws, size_t ws_size,
                              hipStream_t stream) {
    const float* x = (const float*)d_in[0];
    const float* w = (const float*)d_in[1];
    const float* b = (const float*)d_in[2];
    float* out = (float*)d_out;
    unsigned short* node_bf  = (unsigned short*)d_ws;
    unsigned short* nodeT_bf = node_bf + (size_t)M_TOT * D_MODEL;
    const size_t out_bytes = (size_t)out_size * 4;

    if (d_ws == 0 || ws_size < WS_NEEDED) {
        (void)hipMemsetAsync(d_out, 0x4F, out_bytes, stream);   // ws sentinel
        return;
    }

    (void)hipGetLastError();
    proj_kernel<<<dim3(M_TOT/64, D_MODEL/64), dim3(256), 0, stream>>>(x, w, b, node_bf, nodeT_bf);
    hipError_t ep = hipGetLastError();
    flash_kernel<<<dim3(SEQ/64, BATCH), dim3(256), 0, stream>>>(node_bf, nodeT_bf, out);
    hipError_t ef = hipGetLastError();

    if (ep != hipSuccess) {
        (void)hipMemsetAsync(d_out, 0x49, out_bytes, stream);   // proj launch fail
    } else if (ef != hipSuccess) {
        (void)hipMemsetAsync(d_out, 0x4B, out_bytes, stream);   // flash launch fail
    }
}